// Round 11
// baseline (131.964 us; speedup 1.0000x reference)
//
#include <hip/hip_runtime.h>

// DeepPoly affine transformer — fused single pass over weight.
// Identity: Wp@x + Wm@y = 0.5*( W@(x+y) - |W|@(y-x) )
//           Wp@y + Wm@x = 0.5*( W@(x+y) + |W|@(y-x) )
// mu folded: new_lower = bias + sum( wp*A + wm*B ), A=beta*l0, B=lmbda*u0+mu
//            new_upper = bias + sum( wp*B + wm*A )
//
// R11: R4's main loop (the best performer: ROWS=8, SPLITK=2, KITER=4,
// compiler-scheduled full unroll, cols direct from L2) kept bit-for-bit;
// epilogue folded into the main kernel via split-K fixup (per-row-group
// atomic counter; last block combines + writes out).  Session model:
// HBM read is MSHR-capped at ~4.8 TB/s (all 4 structurally different
// schedules pinned there), L2-hit col loads overlap free, so main time
// floor = 134 MB / 4.8 TB/s ~ 28 us; remaining lever is launch overhead.

constexpr int N_OUT  = 4096;
constexpr int N_IN   = 8192;
constexpr int BLK    = 256;             // 4 waves
constexpr int ROWS   = 8;               // output rows per block
constexpr int SPLITK = 2;
constexpr int KSLICE = N_IN / SPLITK;   // 4096 columns per block
constexpr int CHUNK  = BLK * 4;         // 1024 floats per chunk
constexpr int KITER  = KSLICE / CHUNK;  // 4
constexpr int NGROUP = N_OUT / ROWS;    // 512 row-groups

__device__ __forceinline__ float4 ld4(const float* p) {
    return *reinterpret_cast<const float4*>(p);
}

__device__ __forceinline__ float waveRed(float v) {
#pragma unroll
    for (int off = 32; off > 0; off >>= 1)
        v += __shfl_xor(v, off, 64);
    return v;
}

// ---- pass 1: build the 4 fused column vectors + zero fixup counters ----
__global__ __launch_bounds__(256) void precompute_cols(
        const float* __restrict__ bounds,   // [2, N_IN]
        const float* __restrict__ bounds0,  // [2, N_IN]
        const float* __restrict__ beta,
        const float* __restrict__ lmbda,
        const float* __restrict__ mu,
        float* __restrict__ cols,           // [4, N_IN]
        int* __restrict__ cnt)              // [NGROUP]
{
    const int i = blockIdx.x * 256 + threadIdx.x;
    if (i < NGROUP) cnt[i] = 0;             // re-zeroed every call
    if (i >= N_IN) return;
    const float l  = bounds[i],  u  = bounds[i + N_IN];
    const float l0 = bounds0[i], u0 = bounds0[i + N_IN];
    const float A  = beta[i] * l0;
    const float B  = fmaf(lmbda[i], u0, mu[i]);
    cols[i]             = l + u;   // s1
    cols[i + N_IN]      = u - l;   // d1  (>= 0)
    cols[i + 2 * N_IN]  = A + B;   // s2
    cols[i + 3 * N_IN]  = B - A;   // d2
}

// ---- pass 2: stream the weight once; split-K fixup writes final out ----
__global__ __launch_bounds__(BLK) void deeppoly_main(
        const float* __restrict__ W,
        const float* __restrict__ cols,
        const float* __restrict__ bias,
        float* __restrict__ partials,       // [SPLITK][N_OUT][4]
        int* __restrict__ cnt,              // [NGROUP]
        float* __restrict__ out)            // [2, N_OUT]
{
    const int t  = threadIdx.x;
    const int r0 = blockIdx.x * ROWS;
    const int sk = blockIdx.y;
    const int k0 = sk * KSLICE;

    const float* s1 = cols           + k0;
    const float* d1 = cols + N_IN    + k0;
    const float* s2 = cols + 2*N_IN  + k0;
    const float* d2 = cols + 3*N_IN  + k0;
    const float* Wb = W + (size_t)r0 * N_IN + k0;

    float aS[ROWS], aD[ROWS], aMS[ROWS], aMD[ROWS];
#pragma unroll
    for (int r = 0; r < ROWS; ++r) {
        aS[r] = 0.f; aD[r] = 0.f; aMS[r] = 0.f; aMD[r] = 0.f;
    }

    // ---- R4's compiler-scheduled full unroll, unchanged ----
#pragma unroll
    for (int k = 0; k < KITER; ++k) {
        const int c = (t + k * BLK) * 4;

        const float4 s1v = ld4(s1 + c);
        const float4 d1v = ld4(d1 + c);
        const float4 s2v = ld4(s2 + c);
        const float4 d2v = ld4(d2 + c);

#pragma unroll
        for (int r = 0; r < ROWS; ++r) {
            const float4 wv = ld4(Wb + (size_t)r * N_IN + c);

#define UPD(wc, s1c, d1c, s2c, d2c)                      \
            {                                            \
                const float w_ = (wc);                   \
                const float a_ = fabsf(w_);              \
                aS[r]  = fmaf(w_, (s1c), aS[r]);         \
                aD[r]  = fmaf(a_, (d1c), aD[r]);         \
                aMS[r] = fmaf(w_, (s2c), aMS[r]);        \
                aMD[r] = fmaf(a_, (d2c), aMD[r]);        \
            }
            UPD(wv.x, s1v.x, d1v.x, s2v.x, d2v.x)
            UPD(wv.y, s1v.y, d1v.y, s2v.y, d2v.y)
            UPD(wv.z, s1v.z, d1v.z, s2v.z, d2v.z)
            UPD(wv.w, s1v.w, d1v.w, s2v.w, d2v.w)
#undef UPD
        }
    }

    // ---- block reduction: wave shuffle-reduce, then LDS across 4 waves ----
    __shared__ float red[BLK / 64][ROWS][4];
    __shared__ int isLast;
    const int wave = t >> 6;
    const int lane = t & 63;

#pragma unroll
    for (int r = 0; r < ROWS; ++r) {
        const float vS  = waveRed(aS[r]);
        const float vD  = waveRed(aD[r]);
        const float vMS = waveRed(aMS[r]);
        const float vMD = waveRed(aMD[r]);
        if (lane == 0) {
            red[wave][r][0] = vS;
            red[wave][r][1] = vD;
            red[wave][r][2] = vMS;
            red[wave][r][3] = vMD;
        }
    }
    __syncthreads();

    // 32 threads write this block's partial sums
    if (t < ROWS * 4) {
        const int r = t >> 2;
        const int s = t & 3;
        float acc = 0.f;
#pragma unroll
        for (int w = 0; w < BLK / 64; ++w)
            acc += red[w][r][s];
        partials[((size_t)sk * N_OUT + (r0 + r)) * 4 + s] = acc;
    }
    __threadfence();          // make partials device-visible (release)
    __syncthreads();

    if (t == 0)
        isLast = (atomicAdd(&cnt[blockIdx.x], 1) == SPLITK - 1);
    __syncthreads();

    // ---- last-arriving block of this row-group finalizes 8 outputs ----
    if (isLast && t < ROWS) {
        __threadfence();      // acquire: other block's partials
        const int i = r0 + t;
        float p[4];
#pragma unroll
        for (int s = 0; s < 4; ++s) {
            float acc = 0.f;
#pragma unroll
            for (int sk2 = 0; sk2 < SPLITK; ++sk2)
                acc += partials[((size_t)sk2 * N_OUT + i) * 4 + s];
            p[s] = acc;
        }
        const float bi = bias[i];
        const float lower     = fmaf(0.5f, p[0] - p[1], bi);
        const float upper     = fmaf(0.5f, p[0] + p[1], bi);
        const float new_lower = fmaf(0.5f, p[2] - p[3], bi);
        const float new_upper = fmaf(0.5f, p[2] + p[3], bi);

        out[i]         = fmaxf(lower, new_lower);
        out[N_OUT + i] = fminf(upper, new_upper);
    }
}

extern "C" void kernel_launch(void* const* d_in, const int* in_sizes, int n_in,
                              void* d_out, int out_size, void* d_ws, size_t ws_size,
                              hipStream_t stream) {
    const float* W       = (const float*)d_in[0];
    const float* bias    = (const float*)d_in[1];
    const float* bounds  = (const float*)d_in[2];
    const float* bounds0 = (const float*)d_in[3];
    const float* beta    = (const float*)d_in[4];
    const float* lmbda   = (const float*)d_in[5];
    const float* mu      = (const float*)d_in[6];
    float* out      = (float*)d_out;
    float* cols     = (float*)d_ws;                       // 4*N_IN floats (128 KB)
    float* partials = (float*)d_ws + 4 * N_IN;            // SPLITK*N_OUT*4 floats (128 KB)
    int*   cnt      = (int*)((float*)d_ws + 4 * N_IN + SPLITK * N_OUT * 4); // 512 ints

    precompute_cols<<<N_IN / 256, 256, 0, stream>>>(
        bounds, bounds0, beta, lmbda, mu, cols, cnt);

    dim3 grid(N_OUT / ROWS, SPLITK);
    deeppoly_main<<<grid, BLK, 0, stream>>>(W, cols, bias, partials, cnt, out);
}

// Round 12
// 31.470 us; speedup vs baseline: 4.1932x; 4.1932x over previous
//
#include <hip/hip_runtime.h>

// DeepPoly affine transformer — fused single pass over weight.
// Identity: Wp@x + Wm@y = 0.5*( W@(x+y) - |W|@(y-x) )
//           Wp@y + Wm@x = 0.5*( W@(x+y) + |W|@(y-x) )
// mu folded: new_lower = bias + sum( wp*A + wm*B ), A=beta*l0, B=lmbda*u0+mu
//            new_upper = bias + sum( wp*B + wm*A )
//
// R12: R4's main loop kept bit-for-bit EXCEPT the 4 precomputed col
// streams are computed inline from the 7 raw input vectors (all L2/L3-hot;
// R10 proved L2-hit col bytes overlap ~free; VALU has 4x headroom).  This
// deletes the precompute kernel -> 2-launch chain (main + tiny epilogue).
// No fences/atomics (R11 lesson: device-scope threadfence is catastrophic).
// Session model: W stream is L3-resident during timing and pinned at
// ~4.8 TB/s (L3->CU read-path cap) across 5 structurally different
// schedules -> main floor ~28 us; this round removes launch overhead only.

constexpr int N_OUT  = 4096;
constexpr int N_IN   = 8192;
constexpr int BLK    = 256;             // 4 waves
constexpr int ROWS   = 8;               // output rows per block
constexpr int SPLITK = 2;
constexpr int KSLICE = N_IN / SPLITK;   // 4096 columns per block
constexpr int CHUNK  = BLK * 4;         // 1024 floats per chunk
constexpr int KITER  = KSLICE / CHUNK;  // 4

__device__ __forceinline__ float4 ld4(const float* p) {
    return *reinterpret_cast<const float4*>(p);
}

__device__ __forceinline__ float waveRed(float v) {
#pragma unroll
    for (int off = 32; off > 0; off >>= 1)
        v += __shfl_xor(v, off, 64);
    return v;
}

// ---- pass 1: stream the weight once; write split-K partials ----
__global__ __launch_bounds__(BLK) void deeppoly_main(
        const float* __restrict__ W,
        const float* __restrict__ bounds,   // [2, N_IN]
        const float* __restrict__ bounds0,  // [2, N_IN]
        const float* __restrict__ beta,
        const float* __restrict__ lmbda,
        const float* __restrict__ mu,
        float* __restrict__ partials)       // [SPLITK][N_OUT][4]
{
    const int t  = threadIdx.x;
    const int r0 = blockIdx.x * ROWS;
    const int sk = blockIdx.y;
    const int k0 = sk * KSLICE;

    const float* lo  = bounds          + k0;
    const float* up  = bounds  + N_IN  + k0;
    const float* lo0 = bounds0         + k0;
    const float* up0 = bounds0 + N_IN  + k0;
    const float* be  = beta            + k0;
    const float* la  = lmbda           + k0;
    const float* muv = mu              + k0;
    const float* Wb  = W + (size_t)r0 * N_IN + k0;

    float aS[ROWS], aD[ROWS], aMS[ROWS], aMD[ROWS];
#pragma unroll
    for (int r = 0; r < ROWS; ++r) {
        aS[r] = 0.f; aD[r] = 0.f; aMS[r] = 0.f; aMD[r] = 0.f;
    }

    // ---- R4's compiler-scheduled full unroll; cols computed inline ----
#pragma unroll
    for (int k = 0; k < KITER; ++k) {
        const int c = (t + k * BLK) * 4;

        const float4 lv  = ld4(lo  + c);
        const float4 uv  = ld4(up  + c);
        const float4 l0v = ld4(lo0 + c);
        const float4 u0v = ld4(up0 + c);
        const float4 bev = ld4(be  + c);
        const float4 lav = ld4(la  + c);
        const float4 mv  = ld4(muv + c);

        // s1 = l+u ; d1 = u-l ; A = beta*l0 ; B = lmbda*u0 + mu ;
        // s2 = A+B ; d2 = B-A
        float4 s1v, d1v, s2v, d2v;
        {
            const float Ax = bev.x * l0v.x, Ay = bev.y * l0v.y,
                        Az = bev.z * l0v.z, Aw = bev.w * l0v.w;
            const float Bx = fmaf(lav.x, u0v.x, mv.x),
                        By = fmaf(lav.y, u0v.y, mv.y),
                        Bz = fmaf(lav.z, u0v.z, mv.z),
                        Bw = fmaf(lav.w, u0v.w, mv.w);
            s1v = make_float4(lv.x + uv.x, lv.y + uv.y, lv.z + uv.z, lv.w + uv.w);
            d1v = make_float4(uv.x - lv.x, uv.y - lv.y, uv.z - lv.z, uv.w - lv.w);
            s2v = make_float4(Ax + Bx, Ay + By, Az + Bz, Aw + Bw);
            d2v = make_float4(Bx - Ax, By - Ay, Bz - Az, Bw - Aw);
        }

#pragma unroll
        for (int r = 0; r < ROWS; ++r) {
            const float4 wv = ld4(Wb + (size_t)r * N_IN + c);

#define UPD(wc, s1c, d1c, s2c, d2c)                      \
            {                                            \
                const float w_ = (wc);                   \
                const float a_ = fabsf(w_);              \
                aS[r]  = fmaf(w_, (s1c), aS[r]);         \
                aD[r]  = fmaf(a_, (d1c), aD[r]);         \
                aMS[r] = fmaf(w_, (s2c), aMS[r]);        \
                aMD[r] = fmaf(a_, (d2c), aMD[r]);        \
            }
            UPD(wv.x, s1v.x, d1v.x, s2v.x, d2v.x)
            UPD(wv.y, s1v.y, d1v.y, s2v.y, d2v.y)
            UPD(wv.z, s1v.z, d1v.z, s2v.z, d2v.z)
            UPD(wv.w, s1v.w, d1v.w, s2v.w, d2v.w)
#undef UPD
        }
    }

    // ---- block reduction: wave shuffle-reduce, then LDS across 4 waves ----
    __shared__ float red[BLK / 64][ROWS][4];
    const int wave = t >> 6;
    const int lane = t & 63;

#pragma unroll
    for (int r = 0; r < ROWS; ++r) {
        const float vS  = waveRed(aS[r]);
        const float vD  = waveRed(aD[r]);
        const float vMS = waveRed(aMS[r]);
        const float vMD = waveRed(aMD[r]);
        if (lane == 0) {
            red[wave][r][0] = vS;
            red[wave][r][1] = vD;
            red[wave][r][2] = vMS;
            red[wave][r][3] = vMD;
        }
    }
    __syncthreads();

    if (t < ROWS * 4) {
        const int r = t >> 2;
        const int s = t & 3;
        float acc = 0.f;
#pragma unroll
        for (int w = 0; w < BLK / 64; ++w)
            acc += red[w][r][s];
        partials[((size_t)sk * N_OUT + (r0 + r)) * 4 + s] = acc;
    }
}

// ---- pass 2: combine split-K partials + bias + tighter-bound select ----
__global__ __launch_bounds__(256) void deeppoly_epilogue(
        const float* __restrict__ partials, // [SPLITK][N_OUT][4]
        const float* __restrict__ bias,
        float* __restrict__ out)            // [2, N_OUT]
{
    const int i = blockIdx.x * 256 + threadIdx.x;
    if (i >= N_OUT) return;

    float4 p = ld4(partials + (size_t)i * 4);
#pragma unroll
    for (int sk = 1; sk < SPLITK; ++sk) {
        const float4 q = ld4(partials + ((size_t)sk * N_OUT + i) * 4);
        p.x += q.x; p.y += q.y; p.z += q.z; p.w += q.w;
    }
    const float bi = bias[i];
    const float lower     = fmaf(0.5f, p.x - p.y, bi);
    const float upper     = fmaf(0.5f, p.x + p.y, bi);
    const float new_lower = fmaf(0.5f, p.z - p.w, bi);
    const float new_upper = fmaf(0.5f, p.z + p.w, bi);

    out[i]         = fmaxf(lower, new_lower);
    out[N_OUT + i] = fminf(upper, new_upper);
}

extern "C" void kernel_launch(void* const* d_in, const int* in_sizes, int n_in,
                              void* d_out, int out_size, void* d_ws, size_t ws_size,
                              hipStream_t stream) {
    const float* W       = (const float*)d_in[0];
    const float* bias    = (const float*)d_in[1];
    const float* bounds  = (const float*)d_in[2];
    const float* bounds0 = (const float*)d_in[3];
    const float* beta    = (const float*)d_in[4];
    const float* lmbda   = (const float*)d_in[5];
    const float* mu      = (const float*)d_in[6];
    float* out      = (float*)d_out;
    float* partials = (float*)d_ws;                 // SPLITK*N_OUT*4 floats (128 KB)

    dim3 grid(N_OUT / ROWS, SPLITK);
    deeppoly_main<<<grid, BLK, 0, stream>>>(
        W, bounds, bounds0, beta, lmbda, mu, partials);

    deeppoly_epilogue<<<N_OUT / 256, 256, 0, stream>>>(partials, bias, out);
}